// Round 2
// baseline (3995.808 us; speedup 1.0000x reference)
//
#include <hip/hip_runtime.h>
#include <hip/hip_bf16.h>
#include <stdint.h>

#define B_ 128
#define T_ 255
#define N_ 256
#define H_ 256

typedef _Float16 f16;
typedef _Float16 f16x2 __attribute__((ext_vector_type(2)));
typedef _Float16 f16x8 __attribute__((ext_vector_type(8)));
typedef float f32x4 __attribute__((ext_vector_type(4)));

static __device__ __forceinline__ float fdot2(uint32_t h, uint32_t u, float acc) {
#if __has_builtin(__builtin_amdgcn_fdot2)
  return __builtin_amdgcn_fdot2(__builtin_bit_cast(f16x2, h),
                                __builtin_bit_cast(f16x2, u), acc, false);
#else
  f16x2 a = __builtin_bit_cast(f16x2, h);
  f16x2 b = __builtin_bit_cast(f16x2, u);
  return acc + (float)a.x * (float)b.x + (float)a.y * (float)b.y;
#endif
}

// ---------------- K0: pack W_lstm (transposed) and U_lstm (k-pair packed) to f16
__global__ __launch_bounds__(256) void k0_pack(const float* __restrict__ Wl,
                                               const float* __restrict__ Ul,
                                               uint32_t* __restrict__ u_packed,
                                               f16* __restrict__ wt) {
  int idx = blockIdx.x * 256 + threadIdx.x;
  if (idx < 256 * 1024) {              // wt[n][k] = Wl[k][n]
    int n = idx >> 8, k = idx & 255;
    wt[n * 256 + k] = (f16)Wl[k * 1024 + n];
  }
  if (idx < 128 * 1024) {              // u_packed[p][c] = (U[2p][c], U[2p+1][c])
    int p = idx >> 10, c = idx & 1023;
    f16x2 v;
    v.x = (f16)Ul[(2 * p) * 1024 + c];
    v.y = (f16)Ul[(2 * p + 1) * 1024 + c];
    u_packed[idx] = __builtin_bit_cast(uint32_t, v);
  }
}

// ---------------- K1: alpha[b][n] = softmax_n( sum_t X[b,t,n] * Wa[512+t] )
__global__ __launch_bounds__(256) void k1_alpha(const float* __restrict__ X,
                                                const float* __restrict__ Wa,
                                                float* __restrict__ alpha) {
  int b = blockIdx.x, n = threadIdx.x;
  const float* xb = X + b * (T_ * N_) + n;
  float a0 = 0.f, a1 = 0.f, a2 = 0.f, a3 = 0.f;
  int t = 0;
  for (; t + 4 <= T_; t += 4) {
    a0 += xb[(t + 0) * N_] * Wa[512 + t + 0];
    a1 += xb[(t + 1) * N_] * Wa[512 + t + 1];
    a2 += xb[(t + 2) * N_] * Wa[512 + t + 2];
    a3 += xb[(t + 3) * N_] * Wa[512 + t + 3];
  }
  for (; t < T_; ++t) a0 += xb[t * N_] * Wa[512 + t];
  float e = (a0 + a1) + (a2 + a3);

  __shared__ float red[4];
  float m = e;
  for (int off = 32; off > 0; off >>= 1) m = fmaxf(m, __shfl_xor(m, off));
  int wid = n >> 6;
  if ((n & 63) == 0) red[wid] = m;
  __syncthreads();
  m = fmaxf(fmaxf(red[0], red[1]), fmaxf(red[2], red[3]));
  float ex = __expf(e - m);
  float s = ex;
  for (int off = 32; off > 0; off >>= 1) s += __shfl_xor(s, off);
  __syncthreads();
  if ((n & 63) == 0) red[wid] = s;
  __syncthreads();
  s = (red[0] + red[1]) + (red[2] + red[3]);
  alpha[b * N_ + n] = ex / s;
}

// ---------------- K2: X_tilde = alpha (broadcast over t) * X   (exact fp32)
__global__ __launch_bounds__(256) void k2_xtilde(const float4* __restrict__ X4,
                                                 const float* __restrict__ alpha,
                                                 float4* __restrict__ out4) {
  int i = blockIdx.x * 256 + threadIdx.x;  // over B*T*64 float4s
  if (i < B_ * T_ * 64) {
    int n4 = i & 63;
    int bt = i >> 6;
    int b = bt / T_;
    const float4* A4 = (const float4*)alpha;
    float4 x = X4[i], al = A4[b * 64 + n4];
    float4 r;
    r.x = x.x * al.x; r.y = x.y * al.y; r.z = x.z * al.z; r.w = x.w * al.w;
    out4[i] = r;
  }
}

// ---------------- K3: XW = X_tilde @ W_lstm + b_lstm  -> f16 (32640 x 1024)
// Also zeroes the k4 handshake flags (stream-ordered before k4; must happen
// every launch because graph replay reuses the workspace).
#define LDA 40  // f16 row stride in LDS (16B-aligned rows, bank-spread)
__global__ __launch_bounds__(256, 2) void k3_gemm(const float* __restrict__ A,
                                                  const f16* __restrict__ Bt,
                                                  const float* __restrict__ bias,
                                                  f16* __restrict__ Cw,
                                                  uint32_t* __restrict__ fz,
                                                  uint32_t* __restrict__ fh) {
  __shared__ f16 As[128 * LDA];
  __shared__ f16 Bs[128 * LDA];
  int tid = threadIdx.x;
  int mt = blockIdx.x;  // 0..254
  int nt = blockIdx.y;  // 0..7
  if (mt == 0 && nt == 0 && tid < 128) {
    fz[tid * 16] = 0;
    fh[tid * 16] = 0;
  }
  int lane = tid & 63, wid = tid >> 6;
  int wm = (wid >> 1) * 64, wn = (wid & 1) * 64;
  f32x4 acc[4][4] = {};

  for (int k0 = 0; k0 < 256; k0 += 32) {
    __syncthreads();
#pragma unroll
    for (int it = 0; it < 4; ++it) {  // A: 128 rows x 32 f32 -> f16
      int idx = tid + it * 256;
      int r = idx >> 3, q = idx & 7;
      float4 v = *(const float4*)(A + (mt * 128 + r) * 256 + k0 + q * 4);
      f16x2 p0, p1;
      p0.x = (f16)v.x; p0.y = (f16)v.y; p1.x = (f16)v.z; p1.y = (f16)v.w;
      uint2 w;
      w.x = __builtin_bit_cast(uint32_t, p0);
      w.y = __builtin_bit_cast(uint32_t, p1);
      *(uint2*)(&As[r * LDA + q * 4]) = w;
    }
#pragma unroll
    for (int it = 0; it < 2; ++it) {  // B (already transposed): 128 rows x 32 f16
      int idx = tid + it * 256;
      int r = idx >> 2, q = idx & 3;
      uint4 v = *(const uint4*)(Bt + (nt * 128 + r) * 256 + k0 + q * 8);
      *(uint4*)(&Bs[r * LDA + q * 8]) = v;
    }
    __syncthreads();
    int kb = (lane >> 4) * 8;
    f16x8 af[4], bf[4];
#pragma unroll
    for (int i = 0; i < 4; ++i)
      af[i] = *(const f16x8*)(&As[(wm + i * 16 + (lane & 15)) * LDA + kb]);
#pragma unroll
    for (int j = 0; j < 4; ++j)
      bf[j] = *(const f16x8*)(&Bs[(wn + j * 16 + (lane & 15)) * LDA + kb]);
#pragma unroll
    for (int i = 0; i < 4; ++i)
#pragma unroll
      for (int j = 0; j < 4; ++j)
        acc[i][j] = __builtin_amdgcn_mfma_f32_16x16x32_f16(af[i], bf[j], acc[i][j], 0, 0, 0);
  }
  int colL = wn + (lane & 15);
  int rowB = wm + (lane >> 4) * 4;
#pragma unroll
  for (int j = 0; j < 4; ++j) {
    int ng = nt * 128 + colL + j * 16;
    float bv = bias[ng];
#pragma unroll
    for (int i = 0; i < 4; ++i)
#pragma unroll
      for (int r = 0; r < 4; ++r) {
        int mg = mt * 128 + rowB + i * 16 + r;
        Cw[mg * 1024 + ng] = (f16)(acc[i][j][r] + bv);
      }
  }
}

// ---------------- K4: sequential LSTM recurrence, TWO blocks per batch.
// 256 blocks x 512 threads: block bid<128 = role A (k-pairs [0,64), gate
// owner) for batch bid; block bid>=128 = role B (k-pairs [64,128)) for batch
// bid-128. Pairing (b, b+128) lands on the same XCD under round-robin
// dispatch (perf heuristic only). 512-thread blocks give a 256-reg/thread
// budget, so each thread holds its FULL U slice (2 cols x 64 pairs = 128
// regs) -- no u-LDS, no remat, and all 256 CUs are active.
// Handshake per step: B -> zBuf (1024 f32 partials) -> flag fz=t+1;
// A gates -> hBuf (128 packed f16x2) -> flag fh=t+1. All cross-block traffic
// uses relaxed AGENT-scope atomics (coherent-point access); data-before-flag
// ordering comes from __syncthreads' vmcnt drain. Tokens are monotonic; k3
// zeroes flags each launch.
__global__ __launch_bounds__(512, 2) void k4_recur(const float* __restrict__ X,
                                                   const uint32_t* __restrict__ u_packed,
                                                   const f16* __restrict__ xwf,
                                                   float* __restrict__ Xenc,
                                                   float* __restrict__ zBuf,
                                                   uint32_t* __restrict__ hBuf,
                                                   uint32_t* __restrict__ fz,
                                                   uint32_t* __restrict__ fh) {
  __shared__ __align__(16) f16 h_lds[256];   // 512 B
  __shared__ __align__(16) float z_lds[1024];  // 4 KB (role A partials)
  int tid = threadIdx.x;
  int bid = blockIdx.x;
  int b = bid & 127;
  int kh = bid >> 7;  // 0 = role A, 1 = role B
  int n2 = tid;       // column pair (n2, n2+512)

  // Full U slice in registers: pairs [kh*64, kh*64+64) for both columns.
  uint32_t urA[64], urB[64];
#pragma unroll
  for (int p = 0; p < 64; ++p) {
    urA[p] = u_packed[(kh * 64 + p) * 1024 + n2];
    urB[p] = u_packed[(kh * 64 + p) * 1024 + n2 + 512];
  }

  float x00 = X[b * (T_ * N_)];
  float c_st = x00;
  if (tid < 256) h_lds[tid] = (f16)x00;
  __syncthreads();

  const f16* xwb = xwf + (size_t)b * T_ * 1024;
  float* encb = Xenc + (size_t)b * T_ * N_;
  const uint4* h4 = (const uint4*)h_lds;
  float* zb = zBuf + (size_t)b * 1024;
  uint32_t* hb = hBuf + (size_t)b * 128;
  uint32_t* fzp = fz + b * 16;
  uint32_t* fhp = fh + b * 16;

  if (kh == 0) {
    // ---------------- role A ----------------
    float xw0 = (float)xwb[n2];
    float xw1 = (float)xwb[n2 + 512];
    for (int t = 0; t < T_; ++t) {
      float xn0 = 0.f, xn1 = 0.f;
      if (t + 1 < T_) {
        xn0 = (float)xwb[(t + 1) * 1024 + n2];
        xn1 = (float)xwb[(t + 1) * 1024 + n2 + 512];
      }
      float p0 = xw0, p1 = 0.f, q0 = xw1, q1 = 0.f;
#pragma unroll
      for (int g = 0; g < 16; ++g) {
        uint4 hh = h4[g];
        p0 = fdot2(hh.x, urA[4 * g + 0], p0);
        p1 = fdot2(hh.y, urA[4 * g + 1], p1);
        p0 = fdot2(hh.z, urA[4 * g + 2], p0);
        p1 = fdot2(hh.w, urA[4 * g + 3], p1);
        q0 = fdot2(hh.x, urB[4 * g + 0], q0);
        q1 = fdot2(hh.y, urB[4 * g + 1], q1);
        q0 = fdot2(hh.z, urB[4 * g + 2], q0);
        q1 = fdot2(hh.w, urB[4 * g + 3], q1);
      }
      z_lds[n2] = p0 + p1;
      z_lds[n2 + 512] = q0 + q1;
      __syncthreads();  // z_lds ready; all waves done with h_lds
      if (tid < 256) {
        if ((tid & 63) == 0) {  // one lane per gate wave spins (wave lockstep)
          uint32_t want = (uint32_t)(t + 1);
          while (__hip_atomic_load(fzp, __ATOMIC_ACQUIRE,
                                   __HIP_MEMORY_SCOPE_AGENT) < want)
            __builtin_amdgcn_s_sleep(1);
        }
        float zi = z_lds[tid] +
                   __hip_atomic_load(&zb[tid], __ATOMIC_RELAXED, __HIP_MEMORY_SCOPE_AGENT);
        float zf = z_lds[256 + tid] +
                   __hip_atomic_load(&zb[256 + tid], __ATOMIC_RELAXED, __HIP_MEMORY_SCOPE_AGENT);
        float zg = z_lds[512 + tid] +
                   __hip_atomic_load(&zb[512 + tid], __ATOMIC_RELAXED, __HIP_MEMORY_SCOPE_AGENT);
        float zo = z_lds[768 + tid] +
                   __hip_atomic_load(&zb[768 + tid], __ATOMIC_RELAXED, __HIP_MEMORY_SCOPE_AGENT);
        float ig = 1.f / (1.f + __expf(-zi));
        float fg = 1.f / (1.f + __expf(-zf));
        float gg = 1.f - 2.f / (1.f + __expf(2.f * zg));
        float og = 1.f / (1.f + __expf(-zo));
        c_st = fg * c_st + ig * gg;
        float hv = og * (1.f - 2.f / (1.f + __expf(2.f * c_st)));
        encb[t * 256 + tid] = hv;
        h_lds[tid] = (f16)hv;
        float pv = __shfl_xor(hv, 1);
        if ((tid & 1) == 0) {
          f16x2 hp;
          hp.x = (f16)hv;
          hp.y = (f16)pv;
          __hip_atomic_store(&hb[tid >> 1], __builtin_bit_cast(uint32_t, hp),
                             __ATOMIC_RELAXED, __HIP_MEMORY_SCOPE_AGENT);
        }
      }
      __syncthreads();  // h_lds ready; hBuf stores drained (vmcnt 0)
      if (tid == 0 && t + 1 < T_)
        __hip_atomic_store(fhp, (uint32_t)(t + 1), __ATOMIC_RELAXED,
                           __HIP_MEMORY_SCOPE_AGENT);
      xw0 = xn0;
      xw1 = xn1;
    }
  } else {
    // ---------------- role B ----------------
    for (int t = 0; t < T_; ++t) {
      float p0 = 0.f, p1 = 0.f, q0 = 0.f, q1 = 0.f;
#pragma unroll
      for (int g = 0; g < 16; ++g) {
        uint4 hh = h4[16 + g];
        p0 = fdot2(hh.x, urA[4 * g + 0], p0);
        p1 = fdot2(hh.y, urA[4 * g + 1], p1);
        p0 = fdot2(hh.z, urA[4 * g + 2], p0);
        p1 = fdot2(hh.w, urA[4 * g + 3], p1);
        q0 = fdot2(hh.x, urB[4 * g + 0], q0);
        q1 = fdot2(hh.y, urB[4 * g + 1], q1);
        q0 = fdot2(hh.z, urB[4 * g + 2], q0);
        q1 = fdot2(hh.w, urB[4 * g + 3], q1);
      }
      __hip_atomic_store(&zb[n2], p0 + p1, __ATOMIC_RELAXED, __HIP_MEMORY_SCOPE_AGENT);
      __hip_atomic_store(&zb[n2 + 512], q0 + q1, __ATOMIC_RELAXED, __HIP_MEMORY_SCOPE_AGENT);
      __syncthreads();  // zBuf stores drained; all waves done with h_lds
      if (tid < 64) {
        if (tid == 0)
          __hip_atomic_store(fzp, (uint32_t)(t + 1), __ATOMIC_RELAXED,
                             __HIP_MEMORY_SCOPE_AGENT);
        if (t + 1 < T_) {
          if (tid == 0) {  // lane 0 spins; wave proceeds in lockstep after
            uint32_t want = (uint32_t)(t + 1);
            while (__hip_atomic_load(fhp, __ATOMIC_ACQUIRE,
                                     __HIP_MEMORY_SCOPE_AGENT) < want)
              __builtin_amdgcn_s_sleep(1);
          }
          uint32_t w0 = __hip_atomic_load(&hb[2 * tid], __ATOMIC_RELAXED,
                                          __HIP_MEMORY_SCOPE_AGENT);
          uint32_t w1 = __hip_atomic_load(&hb[2 * tid + 1], __ATOMIC_RELAXED,
                                          __HIP_MEMORY_SCOPE_AGENT);
          uint32_t* hl = (uint32_t*)h_lds;
          hl[2 * tid] = w0;
          hl[2 * tid + 1] = w1;
        }
      }
      __syncthreads();  // h_lds refreshed for next step
    }
  }
}

extern "C" void kernel_launch(void* const* d_in, const int* in_sizes, int n_in,
                              void* d_out, int out_size, void* d_ws, size_t ws_size,
                              hipStream_t stream) {
  const float* X = (const float*)d_in[0];
  const float* Wa = (const float*)d_in[1];
  const float* Wl = (const float*)d_in[3];
  const float* Ul = (const float*)d_in[4];
  const float* bl = (const float*)d_in[5];
  float* out = (float*)d_out;
  uint8_t* ws = (uint8_t*)d_ws;

  // Live regions:
  //   alpha  @ 0        (128 KB)  -- dead after k2; k4 reuses as hBuf+flags
  //   u_pack @ 131072   (512 KB)
  //   wt     @ 655360   (512 KB)  -- dead after k3; k4 reuses as zBuf
  //   xw     @ 1179648  (~64 MB)
  float* alpha = (float*)ws;
  uint32_t* u_packed = (uint32_t*)(ws + 131072);
  f16* wt = (f16*)(ws + 655360);
  f16* xw = (f16*)(ws + 1179648);

  uint32_t* hBuf = (uint32_t*)ws;                 // 64 KB  (alpha region)
  uint32_t* fz = (uint32_t*)(ws + 65536);         // 8 KB   (alpha region)
  uint32_t* fh = (uint32_t*)(ws + 73728);         // 8 KB   (alpha region)
  float* zBuf = (float*)(ws + 655360);            // 512 KB (wt region)

  k0_pack<<<1024, 256, 0, stream>>>(Wl, Ul, u_packed, wt);
  k1_alpha<<<128, 256, 0, stream>>>(X, Wa, alpha);
  k2_xtilde<<<8160, 256, 0, stream>>>((const float4*)X, alpha, (float4*)out);
  dim3 g3(255, 8);
  k3_gemm<<<g3, 256, 0, stream>>>(out, wt, bl, xw, fz, fh);
  k4_recur<<<256, 512, 0, stream>>>(X, u_packed, xw, out + 8355840,
                                    zBuf, hBuf, fz, fh);
}

// Round 4
// 602.416 us; speedup vs baseline: 6.6330x; 6.6330x over previous
//
#include <hip/hip_runtime.h>
#include <hip/hip_bf16.h>
#include <stdint.h>

#define B_ 128
#define T_ 255
#define N_ 256
#define H_ 256

// k4 quad-split: tid = n*4 + kq. Thread owns k-pairs [kq*32, kq*32+32) for
// the 4 gate columns {n, n+256, n+512, n+768}. 24 pairs/col in registers
// (96 regs), 8 pairs/col in LDS (8 uint4 planes = 128 KB). Gate reduction is
// an in-quad DPP butterfly (no LDS, no extra barrier); gates are computed
// redundantly by all 4 lanes -> ONE barrier per step.
#define UR_ 24

typedef _Float16 f16;
typedef _Float16 f16x2 __attribute__((ext_vector_type(2)));
typedef _Float16 f16x8 __attribute__((ext_vector_type(8)));
typedef float f32x4 __attribute__((ext_vector_type(4)));

static __device__ __forceinline__ float fdot2(uint32_t h, uint32_t u, float acc) {
#if __has_builtin(__builtin_amdgcn_fdot2)
  return __builtin_amdgcn_fdot2(__builtin_bit_cast(f16x2, h),
                                __builtin_bit_cast(f16x2, u), acc, false);
#else
  f16x2 a = __builtin_bit_cast(f16x2, h);
  f16x2 b = __builtin_bit_cast(f16x2, u);
  return acc + (float)a.x * (float)b.x + (float)a.y * (float)b.y;
#endif
}

// quad_perm DPP add: v += select(v, CTRL). 0xB1 = xor1, 0x4E = xor2.
// CTRL must be a compile-time constant (round-3 compile failure).
template <int CTRL>
static __device__ __forceinline__ float dpp_qadd(float v) {
  int x = __builtin_bit_cast(int, v);
  int y = __builtin_amdgcn_update_dpp(0, x, CTRL, 0xF, 0xF, true);
  return v + __builtin_bit_cast(float, y);
}

// ---------------- K0: pack W_lstm (transposed) and U_lstm (k-pair packed) to f16
__global__ __launch_bounds__(256) void k0_pack(const float* __restrict__ Wl,
                                               const float* __restrict__ Ul,
                                               uint32_t* __restrict__ u_packed,
                                               f16* __restrict__ wt) {
  int idx = blockIdx.x * 256 + threadIdx.x;
  if (idx < 256 * 1024) {              // wt[n][k] = Wl[k][n]
    int n = idx >> 8, k = idx & 255;
    wt[n * 256 + k] = (f16)Wl[k * 1024 + n];
  }
  if (idx < 128 * 1024) {              // u_packed[p][c] = (U[2p][c], U[2p+1][c])
    int p = idx >> 10, c = idx & 1023;
    f16x2 v;
    v.x = (f16)Ul[(2 * p) * 1024 + c];
    v.y = (f16)Ul[(2 * p + 1) * 1024 + c];
    u_packed[idx] = __builtin_bit_cast(uint32_t, v);
  }
}

// ---------------- K1: alpha[b][n] = softmax_n( sum_t X[b,t,n] * Wa[512+t] )
__global__ __launch_bounds__(256) void k1_alpha(const float* __restrict__ X,
                                                const float* __restrict__ Wa,
                                                float* __restrict__ alpha) {
  int b = blockIdx.x, n = threadIdx.x;
  const float* xb = X + b * (T_ * N_) + n;
  float a0 = 0.f, a1 = 0.f, a2 = 0.f, a3 = 0.f;
  int t = 0;
  for (; t + 4 <= T_; t += 4) {
    a0 += xb[(t + 0) * N_] * Wa[512 + t + 0];
    a1 += xb[(t + 1) * N_] * Wa[512 + t + 1];
    a2 += xb[(t + 2) * N_] * Wa[512 + t + 2];
    a3 += xb[(t + 3) * N_] * Wa[512 + t + 3];
  }
  for (; t < T_; ++t) a0 += xb[t * N_] * Wa[512 + t];
  float e = (a0 + a1) + (a2 + a3);

  __shared__ float red[4];
  float m = e;
  for (int off = 32; off > 0; off >>= 1) m = fmaxf(m, __shfl_xor(m, off));
  int wid = n >> 6;
  if ((n & 63) == 0) red[wid] = m;
  __syncthreads();
  m = fmaxf(fmaxf(red[0], red[1]), fmaxf(red[2], red[3]));
  float ex = __expf(e - m);
  float s = ex;
  for (int off = 32; off > 0; off >>= 1) s += __shfl_xor(s, off);
  __syncthreads();
  if ((n & 63) == 0) red[wid] = s;
  __syncthreads();
  s = (red[0] + red[1]) + (red[2] + red[3]);
  alpha[b * N_ + n] = ex / s;
}

// ---------------- K2: X_tilde = alpha (broadcast over t) * X   (exact fp32)
__global__ __launch_bounds__(256) void k2_xtilde(const float4* __restrict__ X4,
                                                 const float* __restrict__ alpha,
                                                 float4* __restrict__ out4) {
  int i = blockIdx.x * 256 + threadIdx.x;  // over B*T*64 float4s
  if (i < B_ * T_ * 64) {
    int n4 = i & 63;
    int bt = i >> 6;
    int b = bt / T_;
    const float4* A4 = (const float4*)alpha;
    float4 x = X4[i], al = A4[b * 64 + n4];
    float4 r;
    r.x = x.x * al.x; r.y = x.y * al.y; r.z = x.z * al.z; r.w = x.w * al.w;
    out4[i] = r;
  }
}

// ---------------- K3: XW = X_tilde @ W_lstm + b_lstm  -> f16 (32640 x 1024)
#define LDA 40  // f16 row stride in LDS (16B-aligned rows, bank-spread)
__global__ __launch_bounds__(256, 2) void k3_gemm(const float* __restrict__ A,
                                                  const f16* __restrict__ Bt,
                                                  const float* __restrict__ bias,
                                                  f16* __restrict__ Cw) {
  __shared__ f16 As[128 * LDA];
  __shared__ f16 Bs[128 * LDA];
  int tid = threadIdx.x;
  int mt = blockIdx.x;  // 0..254
  int nt = blockIdx.y;  // 0..7
  int lane = tid & 63, wid = tid >> 6;
  int wm = (wid >> 1) * 64, wn = (wid & 1) * 64;
  f32x4 acc[4][4] = {};

  for (int k0 = 0; k0 < 256; k0 += 32) {
    __syncthreads();
#pragma unroll
    for (int it = 0; it < 4; ++it) {  // A: 128 rows x 32 f32 -> f16
      int idx = tid + it * 256;
      int r = idx >> 3, q = idx & 7;
      float4 v = *(const float4*)(A + (mt * 128 + r) * 256 + k0 + q * 4);
      f16x2 p0, p1;
      p0.x = (f16)v.x; p0.y = (f16)v.y; p1.x = (f16)v.z; p1.y = (f16)v.w;
      uint2 w;
      w.x = __builtin_bit_cast(uint32_t, p0);
      w.y = __builtin_bit_cast(uint32_t, p1);
      *(uint2*)(&As[r * LDA + q * 4]) = w;
    }
#pragma unroll
    for (int it = 0; it < 2; ++it) {  // B (already transposed): 128 rows x 32 f16
      int idx = tid + it * 256;
      int r = idx >> 2, q = idx & 3;
      uint4 v = *(const uint4*)(Bt + (nt * 128 + r) * 256 + k0 + q * 8);
      *(uint4*)(&Bs[r * LDA + q * 8]) = v;
    }
    __syncthreads();
    int kb = (lane >> 4) * 8;
    f16x8 af[4], bf[4];
#pragma unroll
    for (int i = 0; i < 4; ++i)
      af[i] = *(const f16x8*)(&As[(wm + i * 16 + (lane & 15)) * LDA + kb]);
#pragma unroll
    for (int j = 0; j < 4; ++j)
      bf[j] = *(const f16x8*)(&Bs[(wn + j * 16 + (lane & 15)) * LDA + kb]);
#pragma unroll
    for (int i = 0; i < 4; ++i)
#pragma unroll
      for (int j = 0; j < 4; ++j)
        acc[i][j] = __builtin_amdgcn_mfma_f32_16x16x32_f16(af[i], bf[j], acc[i][j], 0, 0, 0);
  }
  int colL = wn + (lane & 15);
  int rowB = wm + (lane >> 4) * 4;
#pragma unroll
  for (int j = 0; j < 4; ++j) {
    int ng = nt * 128 + colL + j * 16;
    float bv = bias[ng];
#pragma unroll
    for (int i = 0; i < 4; ++i)
#pragma unroll
      for (int r = 0; r < 4; ++r) {
        int mg = mt * 128 + rowB + i * 16 + r;
        Cw[mg * 1024 + ng] = (f16)(acc[i][j][r] + bv);
      }
  }
}

// ---------------- K4: sequential LSTM recurrence, one block per batch,
// quad-split with in-wave gate reduction. 1024 threads: tid = n*4 + kq.
// Per step: each thread does 128 fdot2 (4 gate cols x its 32-pair k-slice);
// the quad's 4 partials per gate are summed with 2 DPP quad_perm adds; ALL
// lanes then compute the gates redundantly (no serial gate wave, no z_lds
// round trip). h for step t+1 is written as f16 into a bank-staggered
// 4-replica ping-pong buffer -> ONE __syncthreads per step. The encb global
// store of step t is issued at the top of step t+1 so its vmcnt drain hides
// under the dot phase.
__global__ __launch_bounds__(1024) void k4_recur(const float* __restrict__ X,
                                                 const uint32_t* __restrict__ u_packed,
                                                 const f16* __restrict__ xwf,
                                                 float* __restrict__ Xenc) {
  // u_lds[j][tid], j = c*2+a: uint4 = k-pairs (kq*32+24+4a .. +3) of col n+c*256
  __shared__ __align__(16) uint4 u_lds[8][1024];  // 128 KB
  // h ping-pong, 4 replicas (one per kq), each 64 f16 slice + 8 f16 stagger pad
  __shared__ __align__(16) f16 hrep[2][4 * 72];   // 1152 B
  int tid = threadIdx.x, b = blockIdx.x;
  int n = tid >> 2, kq = tid & 3;
  int kb = kq * 32;  // first k-pair of this thread's slice

  // register U: pairs kb..kb+23 for the 4 gate cols
  uint32_t ur0[UR_], ur1[UR_], ur2[UR_], ur3[UR_];
#pragma unroll
  for (int p = 0; p < UR_; ++p) {
    ur0[p] = u_packed[(kb + p) * 1024 + n];
    ur1[p] = u_packed[(kb + p) * 1024 + n + 256];
    ur2[p] = u_packed[(kb + p) * 1024 + n + 512];
    ur3[p] = u_packed[(kb + p) * 1024 + n + 768];
  }
  // LDS U: pairs kb+24..kb+31
#pragma unroll
  for (int j = 0; j < 8; ++j) {
    int c = j >> 1, a = j & 1;
    int bp = kb + UR_ + 4 * a;
    uint4 v;
    v.x = u_packed[(bp + 0) * 1024 + n + c * 256];
    v.y = u_packed[(bp + 1) * 1024 + n + c * 256];
    v.z = u_packed[(bp + 2) * 1024 + n + c * 256];
    v.w = u_packed[(bp + 3) * 1024 + n + c * 256];
    u_lds[j][tid] = v;
  }

  float x00 = X[b * (T_ * N_)];
  float c_st = x00;
  // init h replica: lane with kq == n>>6 writes unit n into replica kq
  if (kq == (n >> 6)) hrep[0][kq * 72 + (n & 63)] = (f16)x00;
  __syncthreads();

  const f16* xwb = xwf + (size_t)b * T_ * 1024;
  float* encb = Xenc + (size_t)b * T_ * N_;
  int xcol = n + (kq << 8);

  float xwv = (float)xwb[xcol];
  float hv_prev = 0.f;
  for (int t = 0; t < T_; ++t) {
    // deferred encb store from previous step (drains under this dot phase)
    if (t > 0 && kq == 0) encb[(t - 1) * 256 + n] = hv_prev;
    float xn = 0.f;
    if (t + 1 < T_) xn = (float)xwb[(t + 1) * 1024 + xcol];

    const uint4* h4 = (const uint4*)&hrep[t & 1][0];
    int hbase = kq * 9;  // 72 f16 = 9 uint4 per replica

    float z0 = (kq == 0) ? xwv : 0.f;
    float z1 = (kq == 1) ? xwv : 0.f;
    float z2 = (kq == 2) ? xwv : 0.f;
    float z3 = (kq == 3) ? xwv : 0.f;
#pragma unroll
    for (int g = 0; g < 6; ++g) {  // register part: pairs 4g..4g+3
      uint4 hh = h4[hbase + g];
      z0 = fdot2(hh.x, ur0[4 * g + 0], z0);
      z1 = fdot2(hh.x, ur1[4 * g + 0], z1);
      z2 = fdot2(hh.x, ur2[4 * g + 0], z2);
      z3 = fdot2(hh.x, ur3[4 * g + 0], z3);
      z0 = fdot2(hh.y, ur0[4 * g + 1], z0);
      z1 = fdot2(hh.y, ur1[4 * g + 1], z1);
      z2 = fdot2(hh.y, ur2[4 * g + 1], z2);
      z3 = fdot2(hh.y, ur3[4 * g + 1], z3);
      z0 = fdot2(hh.z, ur0[4 * g + 2], z0);
      z1 = fdot2(hh.z, ur1[4 * g + 2], z1);
      z2 = fdot2(hh.z, ur2[4 * g + 2], z2);
      z3 = fdot2(hh.z, ur3[4 * g + 2], z3);
      z0 = fdot2(hh.w, ur0[4 * g + 3], z0);
      z1 = fdot2(hh.w, ur1[4 * g + 3], z1);
      z2 = fdot2(hh.w, ur2[4 * g + 3], z2);
      z3 = fdot2(hh.w, ur3[4 * g + 3], z3);
    }
    {  // LDS part: pairs 24..27 (h g=6) and 28..31 (h g=7)
      uint4 h6 = h4[hbase + 6];
      uint4 h7 = h4[hbase + 7];
      uint4 u;
      u = u_lds[0][tid];
      z0 = fdot2(h6.x, u.x, z0); z0 = fdot2(h6.y, u.y, z0);
      z0 = fdot2(h6.z, u.z, z0); z0 = fdot2(h6.w, u.w, z0);
      u = u_lds[1][tid];
      z0 = fdot2(h7.x, u.x, z0); z0 = fdot2(h7.y, u.y, z0);
      z0 = fdot2(h7.z, u.z, z0); z0 = fdot2(h7.w, u.w, z0);
      u = u_lds[2][tid];
      z1 = fdot2(h6.x, u.x, z1); z1 = fdot2(h6.y, u.y, z1);
      z1 = fdot2(h6.z, u.z, z1); z1 = fdot2(h6.w, u.w, z1);
      u = u_lds[3][tid];
      z1 = fdot2(h7.x, u.x, z1); z1 = fdot2(h7.y, u.y, z1);
      z1 = fdot2(h7.z, u.z, z1); z1 = fdot2(h7.w, u.w, z1);
      u = u_lds[4][tid];
      z2 = fdot2(h6.x, u.x, z2); z2 = fdot2(h6.y, u.y, z2);
      z2 = fdot2(h6.z, u.z, z2); z2 = fdot2(h6.w, u.w, z2);
      u = u_lds[5][tid];
      z2 = fdot2(h7.x, u.x, z2); z2 = fdot2(h7.y, u.y, z2);
      z2 = fdot2(h7.z, u.z, z2); z2 = fdot2(h7.w, u.w, z2);
      u = u_lds[6][tid];
      z3 = fdot2(h6.x, u.x, z3); z3 = fdot2(h6.y, u.y, z3);
      z3 = fdot2(h6.z, u.z, z3); z3 = fdot2(h6.w, u.w, z3);
      u = u_lds[7][tid];
      z3 = fdot2(h7.x, u.x, z3); z3 = fdot2(h7.y, u.y, z3);
      z3 = fdot2(h7.z, u.z, z3); z3 = fdot2(h7.w, u.w, z3);
    }
    // in-quad butterfly: every lane gets full z for unit n
    z0 = dpp_qadd<0xB1>(z0); z1 = dpp_qadd<0xB1>(z1);
    z2 = dpp_qadd<0xB1>(z2); z3 = dpp_qadd<0xB1>(z3);
    z0 = dpp_qadd<0x4E>(z0); z1 = dpp_qadd<0x4E>(z1);
    z2 = dpp_qadd<0x4E>(z2); z3 = dpp_qadd<0x4E>(z3);

    // gates (redundant on all 4 lanes; keeps c_st consistent per quad)
    float ig = 1.f / (1.f + __expf(-z0));
    float fg = 1.f / (1.f + __expf(-z1));
    float gg = 1.f - 2.f / (1.f + __expf(2.f * z2));
    float og = 1.f / (1.f + __expf(-z3));
    c_st = fg * c_st + ig * gg;
    float hv = og * (1.f - 2.f / (1.f + __expf(2.f * c_st)));
    hv_prev = hv;
    // write next-step h into replica kq (only the lane whose slice covers n)
    if (kq == (n >> 6)) hrep[(t + 1) & 1][kq * 72 + (n & 63)] = (f16)hv;
    __syncthreads();
    xwv = xn;
  }
  if (kq == 0) encb[(T_ - 1) * 256 + n] = hv_prev;
}

extern "C" void kernel_launch(void* const* d_in, const int* in_sizes, int n_in,
                              void* d_out, int out_size, void* d_ws, size_t ws_size,
                              hipStream_t stream) {
  const float* X = (const float*)d_in[0];
  const float* Wa = (const float*)d_in[1];
  const float* Wl = (const float*)d_in[3];
  const float* Ul = (const float*)d_in[4];
  const float* bl = (const float*)d_in[5];
  float* out = (float*)d_out;
  uint8_t* ws = (uint8_t*)d_ws;

  float* alpha = (float*)ws;                          // 131072 B
  uint32_t* u_packed = (uint32_t*)(ws + 131072);      // 524288 B
  f16* wt = (f16*)(ws + 655360);                      // 524288 B
  f16* xw = (f16*)(ws + 1179648);                     // 66846720 B (~68 MB total)

  k0_pack<<<1024, 256, 0, stream>>>(Wl, Ul, u_packed, wt);
  k1_alpha<<<128, 256, 0, stream>>>(X, Wa, alpha);
  k2_xtilde<<<8160, 256, 0, stream>>>((const float4*)X, alpha, (float4*)out);
  dim3 g3(255, 8);
  k3_gemm<<<g3, 256, 0, stream>>>(out, wt, bl, xw);
  k4_recur<<<128, 1024, 0, stream>>>(X, u_packed, xw, out + 8355840);
}

// Round 5
// 548.377 us; speedup vs baseline: 7.2866x; 1.0985x over previous
//
#include <hip/hip_runtime.h>
#include <hip/hip_bf16.h>
#include <stdint.h>

#define B_ 128
#define T_ 255
#define N_ 256
#define H_ 256

// k4 k-split layout (round-1 proven, 490us): thread (kh, n2) owns columns n2
// and n2+512, k-pairs [kh*64, kh*64+64). 48 pairs/col in registers (96 regs),
// 16 pairs/col in LDS (8 planes x 1024 cols x uint4 = 128 KB).
// Round-5 change: u-LDS reads interleaved into the register-fdot2 loop.
#define RP2 48
#define LG2 4

typedef _Float16 f16;
typedef _Float16 f16x2 __attribute__((ext_vector_type(2)));
typedef _Float16 f16x8 __attribute__((ext_vector_type(8)));
typedef float f32x4 __attribute__((ext_vector_type(4)));

static __device__ __forceinline__ float fdot2(uint32_t h, uint32_t u, float acc) {
#if __has_builtin(__builtin_amdgcn_fdot2)
  return __builtin_amdgcn_fdot2(__builtin_bit_cast(f16x2, h),
                                __builtin_bit_cast(f16x2, u), acc, false);
#else
  f16x2 a = __builtin_bit_cast(f16x2, h);
  f16x2 b = __builtin_bit_cast(f16x2, u);
  return acc + (float)a.x * (float)b.x + (float)a.y * (float)b.y;
#endif
}

// ---------------- K0: pack W_lstm (transposed) and U_lstm (k-pair packed) to f16
__global__ __launch_bounds__(256) void k0_pack(const float* __restrict__ Wl,
                                               const float* __restrict__ Ul,
                                               uint32_t* __restrict__ u_packed,
                                               f16* __restrict__ wt) {
  int idx = blockIdx.x * 256 + threadIdx.x;
  if (idx < 256 * 1024) {              // wt[n][k] = Wl[k][n]
    int n = idx >> 8, k = idx & 255;
    wt[n * 256 + k] = (f16)Wl[k * 1024 + n];
  }
  if (idx < 128 * 1024) {              // u_packed[p][c] = (U[2p][c], U[2p+1][c])
    int p = idx >> 10, c = idx & 1023;
    f16x2 v;
    v.x = (f16)Ul[(2 * p) * 1024 + c];
    v.y = (f16)Ul[(2 * p + 1) * 1024 + c];
    u_packed[idx] = __builtin_bit_cast(uint32_t, v);
  }
}

// ---------------- K1: alpha[b][n] = softmax_n( sum_t X[b,t,n] * Wa[512+t] )
__global__ __launch_bounds__(256) void k1_alpha(const float* __restrict__ X,
                                                const float* __restrict__ Wa,
                                                float* __restrict__ alpha) {
  int b = blockIdx.x, n = threadIdx.x;
  const float* xb = X + b * (T_ * N_) + n;
  float a0 = 0.f, a1 = 0.f, a2 = 0.f, a3 = 0.f;
  int t = 0;
  for (; t + 4 <= T_; t += 4) {
    a0 += xb[(t + 0) * N_] * Wa[512 + t + 0];
    a1 += xb[(t + 1) * N_] * Wa[512 + t + 1];
    a2 += xb[(t + 2) * N_] * Wa[512 + t + 2];
    a3 += xb[(t + 3) * N_] * Wa[512 + t + 3];
  }
  for (; t < T_; ++t) a0 += xb[t * N_] * Wa[512 + t];
  float e = (a0 + a1) + (a2 + a3);

  __shared__ float red[4];
  float m = e;
  for (int off = 32; off > 0; off >>= 1) m = fmaxf(m, __shfl_xor(m, off));
  int wid = n >> 6;
  if ((n & 63) == 0) red[wid] = m;
  __syncthreads();
  m = fmaxf(fmaxf(red[0], red[1]), fmaxf(red[2], red[3]));
  float ex = __expf(e - m);
  float s = ex;
  for (int off = 32; off > 0; off >>= 1) s += __shfl_xor(s, off);
  __syncthreads();
  if ((n & 63) == 0) red[wid] = s;
  __syncthreads();
  s = (red[0] + red[1]) + (red[2] + red[3]);
  alpha[b * N_ + n] = ex / s;
}

// ---------------- K2: X_tilde = alpha (broadcast over t) * X   (exact fp32)
__global__ __launch_bounds__(256) void k2_xtilde(const float4* __restrict__ X4,
                                                 const float* __restrict__ alpha,
                                                 float4* __restrict__ out4) {
  int i = blockIdx.x * 256 + threadIdx.x;  // over B*T*64 float4s
  if (i < B_ * T_ * 64) {
    int n4 = i & 63;
    int bt = i >> 6;
    int b = bt / T_;
    const float4* A4 = (const float4*)alpha;
    float4 x = X4[i], al = A4[b * 64 + n4];
    float4 r;
    r.x = x.x * al.x; r.y = x.y * al.y; r.z = x.z * al.z; r.w = x.w * al.w;
    out4[i] = r;
  }
}

// ---------------- K3: XW = (alpha .* X) @ W_lstm + b_lstm  -> f16 (32640 x 1024)
// ALPHA-FUSED: reads X directly and applies alpha[b][k] during the A->f16
// pack (same fp32 multiply then f16 convert as the k2+old-k3 path =>
// bitwise-identical xw). Drops the 33 MB x_tilde re-read.
#define LDA 40  // f16 row stride in LDS (16B-aligned rows, bank-spread)
__global__ __launch_bounds__(256, 2) void k3_gemm(const float* __restrict__ Xg,
                                                  const float* __restrict__ alpha,
                                                  const f16* __restrict__ Bt,
                                                  const float* __restrict__ bias,
                                                  f16* __restrict__ Cw) {
  __shared__ f16 As[128 * LDA];
  __shared__ f16 Bs[128 * LDA];
  int tid = threadIdx.x;
  int mt = blockIdx.x;  // 0..254
  int nt = blockIdx.y;  // 0..7
  int lane = tid & 63, wid = tid >> 6;
  int wm = (wid >> 1) * 64, wn = (wid & 1) * 64;
  int b0 = (mt * 128) / T_;          // tile spans at most one batch boundary
  int bnd = (b0 + 1) * T_;
  f32x4 acc[4][4] = {};

  for (int k0 = 0; k0 < 256; k0 += 32) {
    __syncthreads();
#pragma unroll
    for (int it = 0; it < 4; ++it) {  // A: 128 rows x 32 (alpha*X) -> f16
      int idx = tid + it * 256;
      int r = idx >> 3, q = idx & 7;
      int row = mt * 128 + r;
      int b = (row >= bnd) ? (b0 + 1) : b0;
      float4 v = *(const float4*)(Xg + row * 256 + k0 + q * 4);
      float4 al = *(const float4*)(alpha + b * 256 + k0 + q * 4);
      v.x *= al.x; v.y *= al.y; v.z *= al.z; v.w *= al.w;
      f16x2 p0, p1;
      p0.x = (f16)v.x; p0.y = (f16)v.y; p1.x = (f16)v.z; p1.y = (f16)v.w;
      uint2 w;
      w.x = __builtin_bit_cast(uint32_t, p0);
      w.y = __builtin_bit_cast(uint32_t, p1);
      *(uint2*)(&As[r * LDA + q * 4]) = w;
    }
#pragma unroll
    for (int it = 0; it < 2; ++it) {  // B (already transposed): 128 rows x 32 f16
      int idx = tid + it * 256;
      int r = idx >> 2, q = idx & 3;
      uint4 v = *(const uint4*)(Bt + (nt * 128 + r) * 256 + k0 + q * 8);
      *(uint4*)(&Bs[r * LDA + q * 8]) = v;
    }
    __syncthreads();
    int kb = (lane >> 4) * 8;
    f16x8 af[4], bf[4];
#pragma unroll
    for (int i = 0; i < 4; ++i)
      af[i] = *(const f16x8*)(&As[(wm + i * 16 + (lane & 15)) * LDA + kb]);
#pragma unroll
    for (int j = 0; j < 4; ++j)
      bf[j] = *(const f16x8*)(&Bs[(wn + j * 16 + (lane & 15)) * LDA + kb]);
#pragma unroll
    for (int i = 0; i < 4; ++i)
#pragma unroll
      for (int j = 0; j < 4; ++j)
        acc[i][j] = __builtin_amdgcn_mfma_f32_16x16x32_f16(af[i], bf[j], acc[i][j], 0, 0, 0);
  }
  int colL = wn + (lane & 15);
  int rowB = wm + (lane >> 4) * 4;
#pragma unroll
  for (int j = 0; j < 4; ++j) {
    int ng = nt * 128 + colL + j * 16;
    float bv = bias[ng];
#pragma unroll
    for (int i = 0; i < 4; ++i)
#pragma unroll
      for (int r = 0; r < 4; ++r) {
        int mg = mt * 128 + rowB + i * 16 + r;
        Cw[mg * 1024 + ng] = (f16)(acc[i][j][r] + bv);
      }
  }
}

// ---------------- K4: sequential LSTM recurrence, one block per batch.
// Round-1 structure exactly, except the 8 u-LDS b128 reads are interleaved
// into the register-fdot2 loop (4 sub-iterations of {issue 2 loads, 24
// reg-fdot2, consume 8 LDS-fdot2}) to spread LDS-pipe pressure across the
// step instead of bursting it at the end under 16-wave lockstep.
__global__ __launch_bounds__(1024) void k4_recur(const float* __restrict__ X,
                                                 const uint32_t* __restrict__ u_packed,
                                                 const f16* __restrict__ xwf,
                                                 float* __restrict__ Xenc) {
  __shared__ __align__(16) uint32_t u_lds[8 * 1024 * 4];  // 128 KB
  __shared__ __align__(16) f16 h_lds[256];                // 512 B
  __shared__ __align__(16) float z_lds[2048];             // 8 KB ([kh][col])
  int tid = threadIdx.x, b = blockIdx.x;
  int kh = tid >> 9, n2 = tid & 511;

  // register part: pairs [kh*64, kh*64+RP2) for cols n2 and n2+512
  uint32_t urA[RP2], urB[RP2];
  int pbase = kh * 64;
#pragma unroll
  for (int p = 0; p < RP2; ++p) {
    urA[p] = u_packed[(pbase + p) * 1024 + n2];
    urB[p] = u_packed[(pbase + p) * 1024 + n2 + 512];
  }
  // LDS part: plane pl = g*2 + kh2 holds pairs (kh2*64 + RP2 + 4g .. +3)
  // for all 1024 cols, uint4-interleaved.
  {
    uint4* dst = (uint4*)u_lds;
#pragma unroll
    for (int pl = 0; pl < 2 * LG2; ++pl) {
      int kh2 = pl & 1, g = pl >> 1;
      int bp = kh2 * 64 + RP2 + 4 * g;
      uint4 v;
      v.x = u_packed[(bp + 0) * 1024 + tid];
      v.y = u_packed[(bp + 1) * 1024 + tid];
      v.z = u_packed[(bp + 2) * 1024 + tid];
      v.w = u_packed[(bp + 3) * 1024 + tid];
      dst[pl * 1024 + tid] = v;
    }
  }
  float x00 = X[b * (T_ * N_)];
  float c_st = x00;
  if (tid < 256) h_lds[tid] = (f16)x00;
  __syncthreads();

  const f16* xwb = xwf + (size_t)b * T_ * 1024;
  float* encb = Xenc + (size_t)b * T_ * N_;
  const uint4* h4 = (const uint4*)h_lds;
  const uint4* u4 = (const uint4*)u_lds;

  // each thread prefetches xw for its "own" column (== tid), coalesced
  float xwv = (float)xwb[tid];
  for (int t = 0; t < T_; ++t) {
    float xw_nxt = 0.f;
    if (t + 1 < T_) xw_nxt = (float)xwb[(t + 1) * 1024 + tid];

    float zA0 = (kh == 0) ? xwv : 0.f, zA1 = 0.f;  // col n2
    float zB0 = (kh == 0) ? 0.f : xwv, zB1 = 0.f;  // col n2+512
#pragma unroll
    for (int j = 0; j < LG2; ++j) {
      // issue this sub-iteration's u-LDS loads early; ~24 fdot2 of cover
      uint4 uA = u4[(j * 2 + kh) * 1024 + n2];
      uint4 uB = u4[(j * 2 + kh) * 1024 + n2 + 512];
#pragma unroll
      for (int gg = 0; gg < 3; ++gg) {  // register part: pairs 4g..4g+3
        int g = j * 3 + gg;
        uint4 hh = h4[kh * 16 + g];
        zA0 = fdot2(hh.x, urA[4 * g + 0], zA0);
        zA1 = fdot2(hh.y, urA[4 * g + 1], zA1);
        zA0 = fdot2(hh.z, urA[4 * g + 2], zA0);
        zA1 = fdot2(hh.w, urA[4 * g + 3], zA1);
        zB0 = fdot2(hh.x, urB[4 * g + 0], zB0);
        zB1 = fdot2(hh.y, urB[4 * g + 1], zB1);
        zB0 = fdot2(hh.z, urB[4 * g + 2], zB0);
        zB1 = fdot2(hh.w, urB[4 * g + 3], zB1);
      }
      {  // consume LDS group j (h pairs RP2+4j .. +3)
        uint4 hh = h4[kh * 16 + RP2 / 4 + j];
        zA0 = fdot2(hh.x, uA.x, zA0);
        zA1 = fdot2(hh.y, uA.y, zA1);
        zA0 = fdot2(hh.z, uA.z, zA0);
        zA1 = fdot2(hh.w, uA.w, zA1);
        zB0 = fdot2(hh.x, uB.x, zB0);
        zB1 = fdot2(hh.y, uB.y, zB1);
        zB0 = fdot2(hh.z, uB.z, zB0);
        zB1 = fdot2(hh.w, uB.w, zB1);
      }
    }
    z_lds[kh * 1024 + n2] = zA0 + zA1;
    z_lds[kh * 1024 + n2 + 512] = zB0 + zB1;
    __syncthreads();
    if (tid < 256) {
      float zi = z_lds[tid] + z_lds[1024 + tid];
      float zf = z_lds[256 + tid] + z_lds[1280 + tid];
      float zg = z_lds[512 + tid] + z_lds[1536 + tid];
      float zo = z_lds[768 + tid] + z_lds[1792 + tid];
      float ig = 1.f / (1.f + __expf(-zi));
      float fg = 1.f / (1.f + __expf(-zf));
      float gg = 1.f - 2.f / (1.f + __expf(2.f * zg));
      float og = 1.f / (1.f + __expf(-zo));
      c_st = fg * c_st + ig * gg;
      float hv = og * (1.f - 2.f / (1.f + __expf(2.f * c_st)));
      encb[t * 256 + tid] = hv;
      h_lds[tid] = (f16)hv;
    }
    __syncthreads();
    xwv = xw_nxt;
  }
}

extern "C" void kernel_launch(void* const* d_in, const int* in_sizes, int n_in,
                              void* d_out, int out_size, void* d_ws, size_t ws_size,
                              hipStream_t stream) {
  const float* X = (const float*)d_in[0];
  const float* Wa = (const float*)d_in[1];
  const float* Wl = (const float*)d_in[3];
  const float* Ul = (const float*)d_in[4];
  const float* bl = (const float*)d_in[5];
  float* out = (float*)d_out;
  uint8_t* ws = (uint8_t*)d_ws;

  float* alpha = (float*)ws;                          // 131072 B
  uint32_t* u_packed = (uint32_t*)(ws + 131072);      // 524288 B
  f16* wt = (f16*)(ws + 655360);                      // 524288 B
  f16* xw = (f16*)(ws + 1179648);                     // 66846720 B (~68 MB total)

  k0_pack<<<1024, 256, 0, stream>>>(Wl, Ul, u_packed, wt);
  k1_alpha<<<128, 256, 0, stream>>>(X, Wa, alpha);
  k2_xtilde<<<8160, 256, 0, stream>>>((const float4*)X, alpha, (float4*)out);
  dim3 g3(255, 8);
  k3_gemm<<<g3, 256, 0, stream>>>(X, alpha, wt, bl, xw);
  k4_recur<<<128, 1024, 0, stream>>>(X, u_packed, xw, out + 8355840);
}